// Round 5
// baseline (162.617 us; speedup 1.0000x reference)
//
#include <hip/hip_runtime.h>
#include <math.h>

#define SIGMA_BOOST 2.0f
#define EPSILON 1e-6f

// native clang vector type — required for __builtin_nontemporal_load/store
typedef float vfloat4 __attribute__((ext_vector_type(4)));

// ---------------------------------------------------------------------------
// Pre-pass: per-t parameters -> float4 {mean_row, mean_col, sigma, pvalue}
//   mean  = sigmoid(pmean) * (N-1)
//   sigma = (softplus(psigma + SIGMA_BOOST) + EPS) * N
// ---------------------------------------------------------------------------
__global__ void params_kernel(const float2* __restrict__ pmeans,
                              const float* __restrict__ psigmas,
                              const float* __restrict__ pvalues,
                              float4* __restrict__ params, int N) {
    int t = blockIdx.x * blockDim.x + threadIdx.x;
    if (t >= N) return;
    float2 pm = pmeans[t];
    float scale = (float)(N - 1);
    float m0 = __fmul_rn(__fdiv_rn(1.0f, __fadd_rn(1.0f, expf(-pm.x))), scale);
    float m1 = __fmul_rn(__fdiv_rn(1.0f, __fadd_rn(1.0f, expf(-pm.y))), scale);
    float z  = __fadd_rn(psigmas[t], SIGMA_BOOST);
    float sp = __fadd_rn(fmaxf(z, 0.0f), log1pf(expf(-fabsf(z))));
    float sg = __fmul_rn(__fadd_rn(sp, EPSILON), (float)N);
    params[t] = make_float4(m0, m1, sg, pvalues[t]);
}

// ---------------------------------------------------------------------------
// BRANCHLESS per-sample body (this round's change).
// Round-4 post-mortem: 6 divergent branch regions per sample blocked load
// hoisting (VGPR=20 -> no MLP). Branchless version:
//   - gather xb[col] unconditionally: ~80% of lanes hit the two hot clamped
//     lines (x[0]/x[N-1], L1-resident) so a full-wave gather touches only
//     ~15 distinct lines — the branch saved nothing.
//   - rows: degenerate (0 / N-1) lanes ds_add into a PER-LANE dummy slot
//     ly[N + lane] (never read back -> harmless, conflict-free), while
//     register accumulators acc0/accE pick up their contributions via
//     cndmask. No same-address RMW serialization, no exec-mask churn.
// Numerics identical to the round-4 verified kernel.
// ---------------------------------------------------------------------------
__device__ __forceinline__ void sample_bl(
        const float4 p, const float n0, const float n1,
        const float* __restrict__ xb, float* __restrict__ ly,
        const int dummy, const int iN1, const float fN1,
        float& acc0, float& accE) {
    // sample = mean + sigma*noise, deliberately UNFUSED (match numpy rounding)
    float s0 = __fadd_rn(p.x, __fmul_rn(p.z, n0));
    float s1 = __fadd_rn(p.y, __fmul_rn(p.z, n1));
    // np.round = half-to-even = rintf; clamp in float, exact int cvt
    int row = (int)fminf(fmaxf(rintf(s0), 0.0f), fN1);
    int col = (int)fminf(fmaxf(rintf(s1), 0.0f), fN1);
    float xv = xb[col];                       // unconditional gather
    float ctr = __fmul_rn(p.w, xv);
    bool mid = (row != 0) & (row != iN1);
    int slot = mid ? row : dummy;             // v_cndmask, no branch
    atomicAdd(&ly[slot], ctr);                // ds_add_f32, unconditional
    acc0 = __fadd_rn(acc0, (row == 0)   ? ctr : 0.0f);
    accE = __fadd_rn(accE, (row == iN1) ? ctr : 0.0f);
}

// ---------------------------------------------------------------------------
// One block per batch row. LDS = (N + 64) floats: y-row accumulator + 64
// per-lane dummy slots. 2 blocks/CU (needs the >64KB dynamic-LDS attribute).
// 4 samples per step, 1-deep register prefetch of next step's noise.
// ---------------------------------------------------------------------------
template <bool INLINE_PARAMS>
__launch_bounds__(1024, 8)
__global__ void contract_kernel(const float* __restrict__ x,
                                const float2* __restrict__ noise,
                                const float4* __restrict__ params,
                                const float2* __restrict__ pmeans,
                                const float* __restrict__ psigmas,
                                const float* __restrict__ pvalues,
                                float* __restrict__ y, int N) {
    extern __shared__ float ly[];
    const int b = blockIdx.x;
    const int tid = threadIdx.x;
    const int nthr = blockDim.x;

    // zero the N real accumulator slots (dummies never read -> no init)
    float4* ly4 = (float4*)ly;
    const int n4 = N >> 2;
    for (int i = tid; i < n4; i += nthr) ly4[i] = make_float4(0.f, 0.f, 0.f, 0.f);
    __syncthreads();

    const float* xb = x + (size_t)b * N;
    const float fN1 = (float)(N - 1);
    const int iN1 = N - 1;
    const int dummy = N + (tid & 63);
    float acc0 = 0.0f, accE = 0.0f;

    if (!INLINE_PARAMS && ((N >> 1) % (2 * nthr)) == 0) {
        // ---- fast path: 4 t's per step, noise prefetched 1 step ahead ------
        const vfloat4* nb4 = (const vfloat4*)(noise + (size_t)b * N);  // N/2 vecs
        const int npairs = N >> 1;
        const int steps = npairs / (2 * nthr);
        int p0 = tid, p1 = tid + nthr;
        vfloat4 nzA = __builtin_nontemporal_load(&nb4[p0]);
        vfloat4 nzB = __builtin_nontemporal_load(&nb4[p1]);
        for (int s = 0; s < steps; ++s) {
            const vfloat4 curA = nzA, curB = nzB;
            const int q0 = p0, q1 = p1;
            p0 += 2 * nthr; p1 += 2 * nthr;
            if (s + 1 < steps) {               // uniform branch (cheap)
                nzA = __builtin_nontemporal_load(&nb4[p0]);
                nzB = __builtin_nontemporal_load(&nb4[p1]);
            }
            float4 pa = params[2 * q0];
            float4 pb = params[2 * q0 + 1];
            float4 pc = params[2 * q1];
            float4 pd = params[2 * q1 + 1];

            sample_bl(pa, curA.x, curA.y, xb, ly, dummy, iN1, fN1, acc0, accE);
            sample_bl(pb, curA.z, curA.w, xb, ly, dummy, iN1, fN1, acc0, accE);
            sample_bl(pc, curB.x, curB.y, xb, ly, dummy, iN1, fN1, acc0, accE);
            sample_bl(pd, curB.z, curB.w, xb, ly, dummy, iN1, fN1, acc0, accE);
        }
    } else {
        // ---- generic / inline-params fallback (same branchless body) -------
        const float2* nb = noise + (size_t)b * N;
        for (int t = tid; t < N; t += nthr) {
            float4 p;
            if (INLINE_PARAMS) {
                float2 pm = pmeans[t];
                float scale = (float)(N - 1);
                p.x = __fmul_rn(__fdiv_rn(1.0f, __fadd_rn(1.0f, expf(-pm.x))), scale);
                p.y = __fmul_rn(__fdiv_rn(1.0f, __fadd_rn(1.0f, expf(-pm.y))), scale);
                float z  = __fadd_rn(psigmas[t], SIGMA_BOOST);
                float sp = __fadd_rn(fmaxf(z, 0.0f), log1pf(expf(-fabsf(z))));
                p.z = __fmul_rn(__fadd_rn(sp, EPSILON), (float)N);
                p.w = pvalues[t];
            } else {
                p = params[t];
            }
            float2 nz = nb[t];
            sample_bl(p, nz.x, nz.y, xb, ly, dummy, iN1, fN1, acc0, accE);
        }
    }

    // fold register accumulators: wave shfl-reduce, one atomic per wave
    for (int off = 32; off > 0; off >>= 1) {
        acc0 = __fadd_rn(acc0, __shfl_down(acc0, off, 64));
        accE = __fadd_rn(accE, __shfl_down(accE, off, 64));
    }
    if ((tid & 63) == 0) {
        atomicAdd(&ly[0], acc0);
        atomicAdd(&ly[iN1], accE);
    }
    __syncthreads();

    // coalesced nontemporal write-out of the full row
    const vfloat4* lv4 = (const vfloat4*)ly;
    vfloat4* yb4 = (vfloat4*)(y + (size_t)b * N);
    for (int i = tid; i < n4; i += nthr)
        __builtin_nontemporal_store(lv4[i], &yb4[i]);
}

extern "C" void kernel_launch(void* const* d_in, const int* in_sizes, int n_in,
                              void* d_out, int out_size, void* d_ws, size_t ws_size,
                              hipStream_t stream) {
    const float*  x       = (const float*)d_in[0];
    const float2* noise   = (const float2*)d_in[1];
    const float2* pmeans  = (const float2*)d_in[2];
    const float*  psigmas = (const float*)d_in[3];
    const float*  pvalues = (const float*)d_in[4];
    float* y = (float*)d_out;

    const int N = in_sizes[3];          // psigmas is (N,)
    const int B = in_sizes[0] / N;      // x is (B,N)

    const size_t params_bytes = (size_t)N * sizeof(float4);
    const bool use_ws = (ws_size >= params_bytes) && (d_ws != nullptr);

    const int block = 1024;
    // N real slots + 64 per-lane dummy slots
    const size_t lds_bytes = ((size_t)N + 64) * sizeof(float);  // 65.8 KB

    // dynamic LDS >64KB needs the opt-in attribute (verified working round 3)
    (void)hipFuncSetAttribute(
        reinterpret_cast<const void*>(&contract_kernel<false>),
        hipFuncAttributeMaxDynamicSharedMemorySize, (int)lds_bytes);
    (void)hipFuncSetAttribute(
        reinterpret_cast<const void*>(&contract_kernel<true>),
        hipFuncAttributeMaxDynamicSharedMemorySize, (int)lds_bytes);

    if (use_ws) {
        float4* params = (float4*)d_ws;
        params_kernel<<<(N + 255) / 256, 256, 0, stream>>>(pmeans, psigmas,
                                                           pvalues, params, N);
        contract_kernel<false><<<B, block, lds_bytes, stream>>>(
            x, noise, params, nullptr, nullptr, nullptr, y, N);
    } else {
        contract_kernel<true><<<B, block, lds_bytes, stream>>>(
            x, noise, nullptr, pmeans, psigmas, pvalues, y, N);
    }
}

// Round 6
// 150.131 us; speedup vs baseline: 1.0832x; 1.0832x over previous
//
#include <hip/hip_runtime.h>
#include <math.h>

#define SIGMA_BOOST 2.0f
#define EPSILON 1e-6f

// native clang vector type — required for __builtin_nontemporal_load/store
typedef float vfloat4 __attribute__((ext_vector_type(4)));

// ---------------------------------------------------------------------------
// Pre-pass: per-t parameters -> float4 {mean_row, mean_col, sigma, pvalue}
//   mean  = sigmoid(pmean) * (N-1)
//   sigma = (softplus(psigma + SIGMA_BOOST) + EPS) * N
// ---------------------------------------------------------------------------
__global__ void params_kernel(const float2* __restrict__ pmeans,
                              const float* __restrict__ psigmas,
                              const float* __restrict__ pvalues,
                              float4* __restrict__ params, int N) {
    int t = blockIdx.x * blockDim.x + threadIdx.x;
    if (t >= N) return;
    float2 pm = pmeans[t];
    float scale = (float)(N - 1);
    float m0 = __fmul_rn(__fdiv_rn(1.0f, __fadd_rn(1.0f, expf(-pm.x))), scale);
    float m1 = __fmul_rn(__fdiv_rn(1.0f, __fadd_rn(1.0f, expf(-pm.y))), scale);
    float z  = __fadd_rn(psigmas[t], SIGMA_BOOST);
    float sp = __fadd_rn(fmaxf(z, 0.0f), log1pf(expf(-fabsf(z))));
    float sg = __fmul_rn(__fadd_rn(sp, EPSILON), (float)N);
    params[t] = make_float4(m0, m1, sg, pvalues[t]);
}

// ---------------------------------------------------------------------------
// Per-sample body, round 6. Model from r2/r4/r5: LDS atomic RMW costs
// ~4 cyc per ACTIVE LANE (address pattern irrelevant), so the only win is
// reducing active-lane count (~80% of rows clamp to 0/N-1 -> registers).
// r4 did that but its 6 divergent regions serialized the dep chains; r5 was
// branchless but paid all 64 atomic lanes. This version: everything
// branchless EXCEPT a single short exec-masked region around the atomic
// (v_cmp + s_and_saveexec + ds_add + restore; no loads inside, so the
// scheduler can still hoist/pipeline all memory ops).
//   - gather xb[col] unconditional: ~80% of lanes hit the two hot clamped
//     L1-resident lines (r5 proved this is ~free).
//   - rows 0 / N-1 accumulate in registers via cndmask (no atomic lane).
// Numerics bit-identical to the verified kernels.
// ---------------------------------------------------------------------------
__device__ __forceinline__ void sample_m(
        const float4 p, const float n0, const float n1,
        const float* __restrict__ xb, float* __restrict__ ly,
        const int iN1, const float fN1, float& acc0, float& accE) {
    // sample = mean + sigma*noise, deliberately UNFUSED (match numpy rounding)
    float s0 = __fadd_rn(p.x, __fmul_rn(p.z, n0));
    float s1 = __fadd_rn(p.y, __fmul_rn(p.z, n1));
    // np.round = half-to-even = rintf; clamp in float, exact int cvt
    int row = (int)fminf(fmaxf(rintf(s0), 0.0f), fN1);
    int col = (int)fminf(fmaxf(rintf(s1), 0.0f), fN1);
    float xv = xb[col];                         // unconditional gather
    float ctr = __fmul_rn(p.w, xv);
    bool lo = (row == 0);
    bool hi = (row == iN1);
    if (!(lo | hi)) atomicAdd(&ly[row], ctr);   // ~20% of lanes active
    acc0 = __fadd_rn(acc0, lo ? ctr : 0.0f);    // cndmask, branchless
    accE = __fadd_rn(accE, hi ? ctr : 0.0f);
}

// ---------------------------------------------------------------------------
// One block per batch row. 64 KB LDS y-row accumulator; 2 blocks/CU
// (32 waves/CU). 4 samples per step; noise AND params prefetched one step
// ahead so each iteration's loads are in flight during the previous
// iteration's compute.
// ---------------------------------------------------------------------------
template <bool INLINE_PARAMS>
__launch_bounds__(1024, 8)
__global__ void contract_kernel(const float* __restrict__ x,
                                const float2* __restrict__ noise,
                                const float4* __restrict__ params,
                                const float2* __restrict__ pmeans,
                                const float* __restrict__ psigmas,
                                const float* __restrict__ pvalues,
                                float* __restrict__ y, int N) {
    extern __shared__ float ly[];
    const int b = blockIdx.x;
    const int tid = threadIdx.x;
    const int nthr = blockDim.x;

    // zero LDS accumulator (vectorized)
    float4* ly4 = (float4*)ly;
    const int n4 = N >> 2;
    for (int i = tid; i < n4; i += nthr) ly4[i] = make_float4(0.f, 0.f, 0.f, 0.f);
    __syncthreads();

    const float* xb = x + (size_t)b * N;
    const float fN1 = (float)(N - 1);
    const int iN1 = N - 1;
    float acc0 = 0.0f, accE = 0.0f;

    if (!INLINE_PARAMS && ((N >> 1) % (2 * nthr)) == 0) {
        // ---- fast path: 4 t's per step, noise+params prefetched 1 ahead ----
        const vfloat4* nb4 = (const vfloat4*)(noise + (size_t)b * N);  // N/2 vecs
        const int npairs = N >> 1;
        const int steps = npairs / (2 * nthr);
        int q0 = tid, q1 = tid + nthr;
        vfloat4 nzA = __builtin_nontemporal_load(&nb4[q0]);
        vfloat4 nzB = __builtin_nontemporal_load(&nb4[q1]);
        float4 pa = params[2 * q0];
        float4 pb = params[2 * q0 + 1];
        float4 pc = params[2 * q1];
        float4 pd = params[2 * q1 + 1];
        for (int s = 0; s < steps; ++s) {
            const vfloat4 cA = nzA, cB = nzB;
            const float4 qa = pa, qb = pb, qc = pc, qd = pd;
            q0 += 2 * nthr; q1 += 2 * nthr;
            if (s + 1 < steps) {               // uniform branch (cheap)
                nzA = __builtin_nontemporal_load(&nb4[q0]);
                nzB = __builtin_nontemporal_load(&nb4[q1]);
                pa = params[2 * q0];
                pb = params[2 * q0 + 1];
                pc = params[2 * q1];
                pd = params[2 * q1 + 1];
            }
            sample_m(qa, cA.x, cA.y, xb, ly, iN1, fN1, acc0, accE);
            sample_m(qb, cA.z, cA.w, xb, ly, iN1, fN1, acc0, accE);
            sample_m(qc, cB.x, cB.y, xb, ly, iN1, fN1, acc0, accE);
            sample_m(qd, cB.z, cB.w, xb, ly, iN1, fN1, acc0, accE);
        }
    } else {
        // ---- generic / inline-params fallback (same masked body) -----------
        const float2* nb = noise + (size_t)b * N;
        for (int t = tid; t < N; t += nthr) {
            float4 p;
            if (INLINE_PARAMS) {
                float2 pm = pmeans[t];
                float scale = (float)(N - 1);
                p.x = __fmul_rn(__fdiv_rn(1.0f, __fadd_rn(1.0f, expf(-pm.x))), scale);
                p.y = __fmul_rn(__fdiv_rn(1.0f, __fadd_rn(1.0f, expf(-pm.y))), scale);
                float z  = __fadd_rn(psigmas[t], SIGMA_BOOST);
                float sp = __fadd_rn(fmaxf(z, 0.0f), log1pf(expf(-fabsf(z))));
                p.z = __fmul_rn(__fadd_rn(sp, EPSILON), (float)N);
                p.w = pvalues[t];
            } else {
                p = params[t];
            }
            float2 nz = nb[t];
            sample_m(p, nz.x, nz.y, xb, ly, iN1, fN1, acc0, accE);
        }
    }

    // fold register accumulators: wave shfl-reduce, one atomic per wave
    for (int off = 32; off > 0; off >>= 1) {
        acc0 = __fadd_rn(acc0, __shfl_down(acc0, off, 64));
        accE = __fadd_rn(accE, __shfl_down(accE, off, 64));
    }
    if ((tid & 63) == 0) {
        atomicAdd(&ly[0], acc0);
        atomicAdd(&ly[iN1], accE);
    }
    __syncthreads();

    // coalesced nontemporal write-out of the full row
    const vfloat4* lv4 = (const vfloat4*)ly;
    vfloat4* yb4 = (vfloat4*)(y + (size_t)b * N);
    for (int i = tid; i < n4; i += nthr)
        __builtin_nontemporal_store(lv4[i], &yb4[i]);
}

extern "C" void kernel_launch(void* const* d_in, const int* in_sizes, int n_in,
                              void* d_out, int out_size, void* d_ws, size_t ws_size,
                              hipStream_t stream) {
    const float*  x       = (const float*)d_in[0];
    const float2* noise   = (const float2*)d_in[1];
    const float2* pmeans  = (const float2*)d_in[2];
    const float*  psigmas = (const float*)d_in[3];
    const float*  pvalues = (const float*)d_in[4];
    float* y = (float*)d_out;

    const int N = in_sizes[3];          // psigmas is (N,)
    const int B = in_sizes[0] / N;      // x is (B,N)

    const size_t params_bytes = (size_t)N * sizeof(float4);
    const bool use_ws = (ws_size >= params_bytes) && (d_ws != nullptr);

    const int block = 1024;
    const size_t lds_bytes = (size_t)N * sizeof(float);  // 64 KB at N=16384

    if (use_ws) {
        float4* params = (float4*)d_ws;
        params_kernel<<<(N + 255) / 256, 256, 0, stream>>>(pmeans, psigmas,
                                                           pvalues, params, N);
        contract_kernel<false><<<B, block, lds_bytes, stream>>>(
            x, noise, params, nullptr, nullptr, nullptr, y, N);
    } else {
        contract_kernel<true><<<B, block, lds_bytes, stream>>>(
            x, noise, nullptr, pmeans, psigmas, pvalues, y, N);
    }
}

// Round 7
// 147.885 us; speedup vs baseline: 1.0996x; 1.0152x over previous
//
#include <hip/hip_runtime.h>
#include <math.h>

#define SIGMA_BOOST 2.0f
#define EPSILON 1e-6f

// native clang vector type — required for __builtin_nontemporal_load/store
typedef float vfloat4 __attribute__((ext_vector_type(4)));

// ---------------------------------------------------------------------------
// Pre-pass: per-t parameters -> float4 {mean_row, mean_col, sigma, pvalue}
//   mean  = sigmoid(pmean) * (N-1)
//   sigma = (softplus(psigma + SIGMA_BOOST) + EPS) * N
// ---------------------------------------------------------------------------
__global__ void params_kernel(const float2* __restrict__ pmeans,
                              const float* __restrict__ psigmas,
                              const float* __restrict__ pvalues,
                              float4* __restrict__ params, int N) {
    int t = blockIdx.x * blockDim.x + threadIdx.x;
    if (t >= N) return;
    float2 pm = pmeans[t];
    float scale = (float)(N - 1);
    float m0 = __fmul_rn(__fdiv_rn(1.0f, __fadd_rn(1.0f, expf(-pm.x))), scale);
    float m1 = __fmul_rn(__fdiv_rn(1.0f, __fadd_rn(1.0f, expf(-pm.y))), scale);
    float z  = __fadd_rn(psigmas[t], SIGMA_BOOST);
    float sp = __fadd_rn(fmaxf(z, 0.0f), log1pf(expf(-fabsf(z))));
    float sg = __fmul_rn(__fadd_rn(sp, EPSILON), (float)N);
    params[t] = make_float4(m0, m1, sg, pvalues[t]);
}

// ---------------------------------------------------------------------------
// Round-7 insight: r4 == r6 == 43 us proved load-prefetch bought nothing.
// Cause: vmcnt is IN-ORDER — the atomics wait on the gathers (newest vmem),
// which forces waiting on the younger-issued... actually on ALL older
// outstanding loads incl. next step's HBM prefetch. Every step exposed a
// full gather+HBM latency chain. Fix: 2-deep SOFTWARE PIPELINE with the
// split at the GATHER: per iteration issue L(s+2) raw loads, G(s+1) index
// compute + gather issue (from registers loaded 1+ iteration ago), C(s)
// masked atomics on values gathered 1 iteration ago. Every waitcnt is on
// ops >= 1 iteration old -> counted vmcnt, ~no exposed latency.
// 2 samples per step so both rotating register sets fit <= 64 VGPR
// (2 blocks/CU). Rotation via named A/B sets in a x2-unrolled loop (no
// runtime-indexed arrays -> no scratch). Numerics bit-identical.
// ---------------------------------------------------------------------------
__device__ __forceinline__ void load_step(const vfloat4* __restrict__ nb4,
                                          const float4* __restrict__ params,
                                          int q, vfloat4& nz, float4& pA,
                                          float4& pB) {
    nz = __builtin_nontemporal_load(&nb4[q]);
    pA = params[2 * q];
    pB = params[2 * q + 1];
}

__device__ __forceinline__ void gather_step(const vfloat4 nz, const float4 pA,
                                            const float4 pB,
                                            const float* __restrict__ xb,
                                            const float fN1,
                                            int& r0, int& r1, float& w0,
                                            float& w1, float& xv0, float& xv1) {
    // sample = mean + sigma*noise, deliberately UNFUSED (match numpy rounding)
    float s0 = __fadd_rn(pA.x, __fmul_rn(pA.z, nz.x));
    float s1 = __fadd_rn(pA.y, __fmul_rn(pA.z, nz.y));
    float s2 = __fadd_rn(pB.x, __fmul_rn(pB.z, nz.z));
    float s3 = __fadd_rn(pB.y, __fmul_rn(pB.z, nz.w));
    // np.round = half-to-even = rintf; clamp in float, exact int cvt
    r0     = (int)fminf(fmaxf(rintf(s0), 0.0f), fN1);
    int c0 = (int)fminf(fmaxf(rintf(s1), 0.0f), fN1);
    r1     = (int)fminf(fmaxf(rintf(s2), 0.0f), fN1);
    int c1 = (int)fminf(fmaxf(rintf(s3), 0.0f), fN1);
    w0 = pA.w; w1 = pB.w;
    xv0 = xb[c0];                 // unconditional gathers (hot lines are ~free)
    xv1 = xb[c1];
}

__device__ __forceinline__ void commit_step(float* __restrict__ ly,
                                            const int iN1, int r0, int r1,
                                            float w0, float w1, float xv0,
                                            float xv1, float& acc0,
                                            float& accE) {
    float ctr0 = __fmul_rn(w0, xv0);
    float ctr1 = __fmul_rn(w1, xv1);
    bool lo0 = (r0 == 0), hi0 = (r0 == iN1);
    bool lo1 = (r1 == 0), hi1 = (r1 == iN1);
    if (!(lo0 | hi0)) atomicAdd(&ly[r0], ctr0);   // ~20% of lanes active
    if (!(lo1 | hi1)) atomicAdd(&ly[r1], ctr1);
    acc0 = __fadd_rn(acc0, lo0 ? ctr0 : 0.0f);    // cndmask, branchless
    accE = __fadd_rn(accE, hi0 ? ctr0 : 0.0f);
    acc0 = __fadd_rn(acc0, lo1 ? ctr1 : 0.0f);
    accE = __fadd_rn(accE, hi1 ? ctr1 : 0.0f);
}

// ---------------------------------------------------------------------------
// One block per batch row. 64 KB LDS y-row accumulator; 2 blocks/CU.
// ---------------------------------------------------------------------------
template <bool INLINE_PARAMS>
__launch_bounds__(1024, 8)
__global__ void contract_kernel(const float* __restrict__ x,
                                const float2* __restrict__ noise,
                                const float4* __restrict__ params,
                                const float2* __restrict__ pmeans,
                                const float* __restrict__ psigmas,
                                const float* __restrict__ pvalues,
                                float* __restrict__ y, int N) {
    extern __shared__ float ly[];
    const int b = blockIdx.x;
    const int tid = threadIdx.x;
    const int nthr = blockDim.x;

    // zero LDS accumulator (vectorized)
    float4* ly4 = (float4*)ly;
    const int n4 = N >> 2;
    for (int i = tid; i < n4; i += nthr) ly4[i] = make_float4(0.f, 0.f, 0.f, 0.f);
    __syncthreads();

    const float* xb = x + (size_t)b * N;
    const float fN1 = (float)(N - 1);
    const int iN1 = N - 1;
    float acc0 = 0.0f, accE = 0.0f;

    const int steps = ((N >> 1) % nthr == 0) ? (N >> 1) / nthr : 0;

    if (!INLINE_PARAMS && steps >= 2 && (steps % 2) == 0) {
        // ---- 2-deep software pipeline, 2 samples per step ------------------
        const vfloat4* nb4 = (const vfloat4*)(noise + (size_t)b * N); // N/2 vecs

        vfloat4 nzA, nzB;
        float4 paA, pbA, paB, pbB;
        int   r0A, r1A, r0B, r1B;
        float w0A, w1A, w0B, w1B;
        float x0A, x1A, x0B, x1B;

        // prologue: loads for steps 0 and 1; gathers for step 0
        load_step(nb4, params, 0 * nthr + tid, nzA, paA, pbA);
        load_step(nb4, params, 1 * nthr + tid, nzB, paB, pbB);
        gather_step(nzA, paA, pbA, xb, fN1, r0A, r1A, w0A, w1A, x0A, x1A);

        for (int s = 0; s < steps; s += 2) {
            if (s + 2 < steps)
                load_step(nb4, params, (s + 2) * nthr + tid, nzA, paA, pbA);
            gather_step(nzB, paB, pbB, xb, fN1, r0B, r1B, w0B, w1B, x0B, x1B);
            commit_step(ly, iN1, r0A, r1A, w0A, w1A, x0A, x1A, acc0, accE);
            if (s + 3 < steps)
                load_step(nb4, params, (s + 3) * nthr + tid, nzB, paB, pbB);
            if (s + 2 < steps)
                gather_step(nzA, paA, pbA, xb, fN1, r0A, r1A, w0A, w1A, x0A, x1A);
            commit_step(ly, iN1, r0B, r1B, w0B, w1B, x0B, x1B, acc0, accE);
        }
    } else {
        // ---- generic / inline-params fallback (round-6 masked body) --------
        const float2* nb = noise + (size_t)b * N;
        for (int t = tid; t < N; t += nthr) {
            float4 p;
            if (INLINE_PARAMS) {
                float2 pm = pmeans[t];
                float scale = (float)(N - 1);
                p.x = __fmul_rn(__fdiv_rn(1.0f, __fadd_rn(1.0f, expf(-pm.x))), scale);
                p.y = __fmul_rn(__fdiv_rn(1.0f, __fadd_rn(1.0f, expf(-pm.y))), scale);
                float z  = __fadd_rn(psigmas[t], SIGMA_BOOST);
                float sp = __fadd_rn(fmaxf(z, 0.0f), log1pf(expf(-fabsf(z))));
                p.z = __fmul_rn(__fadd_rn(sp, EPSILON), (float)N);
                p.w = pvalues[t];
            } else {
                p = params[t];
            }
            float2 nz = nb[t];
            float s0 = __fadd_rn(p.x, __fmul_rn(p.z, nz.x));
            float s1 = __fadd_rn(p.y, __fmul_rn(p.z, nz.y));
            int row = (int)fminf(fmaxf(rintf(s0), 0.0f), fN1);
            int col = (int)fminf(fmaxf(rintf(s1), 0.0f), fN1);
            float xv = xb[col];
            float ctr = __fmul_rn(p.w, xv);
            bool lo = (row == 0);
            bool hi = (row == iN1);
            if (!(lo | hi)) atomicAdd(&ly[row], ctr);
            acc0 = __fadd_rn(acc0, lo ? ctr : 0.0f);
            accE = __fadd_rn(accE, hi ? ctr : 0.0f);
        }
    }

    // fold register accumulators: wave shfl-reduce, one atomic per wave
    for (int off = 32; off > 0; off >>= 1) {
        acc0 = __fadd_rn(acc0, __shfl_down(acc0, off, 64));
        accE = __fadd_rn(accE, __shfl_down(accE, off, 64));
    }
    if ((tid & 63) == 0) {
        atomicAdd(&ly[0], acc0);
        atomicAdd(&ly[iN1], accE);
    }
    __syncthreads();

    // coalesced nontemporal write-out of the full row
    const vfloat4* lv4 = (const vfloat4*)ly;
    vfloat4* yb4 = (vfloat4*)(y + (size_t)b * N);
    for (int i = tid; i < n4; i += nthr)
        __builtin_nontemporal_store(lv4[i], &yb4[i]);
}

extern "C" void kernel_launch(void* const* d_in, const int* in_sizes, int n_in,
                              void* d_out, int out_size, void* d_ws, size_t ws_size,
                              hipStream_t stream) {
    const float*  x       = (const float*)d_in[0];
    const float2* noise   = (const float2*)d_in[1];
    const float2* pmeans  = (const float2*)d_in[2];
    const float*  psigmas = (const float*)d_in[3];
    const float*  pvalues = (const float*)d_in[4];
    float* y = (float*)d_out;

    const int N = in_sizes[3];          // psigmas is (N,)
    const int B = in_sizes[0] / N;      // x is (B,N)

    const size_t params_bytes = (size_t)N * sizeof(float4);
    const bool use_ws = (ws_size >= params_bytes) && (d_ws != nullptr);

    const int block = 1024;
    const size_t lds_bytes = (size_t)N * sizeof(float);  // 64 KB at N=16384

    if (use_ws) {
        float4* params = (float4*)d_ws;
        params_kernel<<<(N + 255) / 256, 256, 0, stream>>>(pmeans, psigmas,
                                                           pvalues, params, N);
        contract_kernel<false><<<B, block, lds_bytes, stream>>>(
            x, noise, params, nullptr, nullptr, nullptr, y, N);
    } else {
        contract_kernel<true><<<B, block, lds_bytes, stream>>>(
            x, noise, nullptr, pmeans, psigmas, pvalues, y, N);
    }
}